// Round 3
// baseline (276.663 us; speedup 1.0000x reference)
//
#include <hip/hip_runtime.h>

#define G_CONST     9.81f
#define DT_VEL_     0.01f
#define MAX_THRUST_ 39.96f                 // 0.9 * 44.4
#define MAX_ANGLE_  0.5235987755982988f    // 30 deg in rad
#define ALPHA_      0.16666667f            // DT/(TAU+DT) in f32

__device__ __forceinline__ void pid_one(
    const float* rv, const float* mv, const float* pi,
    const float* pe, const float* pd,
    float yaw, float m,
    float& rp0o, float& rp1o, float& th)
{
    const float KP[3] = {2.0f, 2.0f, 4.0f};
    const float KI[3] = {0.5f, 0.5f, 1.0f};
    const float KD[3] = {0.1f, 0.1f, 0.05f};
    float u[3];
#pragma unroll
    for (int c = 0; c < 3; ++c) {
        float err   = rv[c] - mv[c];
        float integ = pi[c] + err * DT_VEL_;
        float d_raw = (err - pe[c]) / DT_VEL_;
        float d     = pd[c] + ALPHA_ * (d_raw - pd[c]);
        float uu    = KP[c] * err + KI[c] * integ + KD[c] * d;
        u[c] = fminf(fmaxf(uu, -6.0f), 6.0f);
    }
    float s, c;
    __sincosf(yaw, &s, &c);
    float rp0 = (s * u[0] - c * u[1]) / G_CONST;
    float rp1 = (c * u[0] + s * u[1]) / G_CONST;
    float mag = sqrtf(rp0 * rp0 + rp1 * rp1);
    float sc  = fminf(MAX_ANGLE_ / (mag + 1e-6f), 1.0f);
    sc = (mag > MAX_ANGLE_) ? sc : 1.0f;
    rp0o = rp0 * sc;
    rp1o = rp1 * sc;
    th = fminf(fmaxf(m * G_CONST + m * u[2], 0.8f * G_CONST * m), MAX_THRUST_);
}

__global__ __launch_bounds__(256) void pos_ctrl_kernel(
    const float* __restrict__ ref_ve,
    const float* __restrict__ meas_ve,
    const float* __restrict__ meas_yaw,
    const float* __restrict__ mass,
    const float* __restrict__ pid_int,
    const float* __restrict__ pid_prev_err,
    const float* __restrict__ pid_prev_d,
    float* __restrict__ out,   // fp32: [n*2 rp interleaved][n thrust]
    int n)
{
    const int t = blockIdx.x * blockDim.x + threadIdx.x;
    const long i0 = (long)t * 4;

    if (i0 + 4 <= n) {
        union V12 { float4 v[3]; float s[12]; };
        union V4  { float4 v;    float s[4];  };
        V12 rv, mv, pi, pe, pd;
        V4 yw, ms;
        const float4* p;
        p = (const float4*)ref_ve       + 3 * (size_t)t; rv.v[0] = p[0]; rv.v[1] = p[1]; rv.v[2] = p[2];
        p = (const float4*)meas_ve      + 3 * (size_t)t; mv.v[0] = p[0]; mv.v[1] = p[1]; mv.v[2] = p[2];
        p = (const float4*)pid_int      + 3 * (size_t)t; pi.v[0] = p[0]; pi.v[1] = p[1]; pi.v[2] = p[2];
        p = (const float4*)pid_prev_err + 3 * (size_t)t; pe.v[0] = p[0]; pe.v[1] = p[1]; pe.v[2] = p[2];
        p = (const float4*)pid_prev_d   + 3 * (size_t)t; pd.v[0] = p[0]; pd.v[1] = p[1]; pd.v[2] = p[2];
        yw.v = ((const float4*)meas_yaw)[t];
        ms.v = ((const float4*)mass)[t];

        union V8 { float4 v[2]; float s[8]; } rp;
        V4 th;
#pragma unroll
        for (int j = 0; j < 4; ++j) {
            const int k = j * 3;
            float rp0, rp1, thr;
            pid_one(&rv.s[k], &mv.s[k], &pi.s[k], &pe.s[k], &pd.s[k],
                    yw.s[j], ms.s[j], rp0, rp1, thr);
            rp.s[j*2 + 0] = rp0;
            rp.s[j*2 + 1] = rp1;
            th.s[j] = thr;
        }
        float4* orp = (float4*)out + 2 * (size_t)t;   // elements 8t..8t+7 (rp pairs for drones 4t..4t+3)
        orp[0] = rp.v[0];
        orp[1] = rp.v[1];
        ((float4*)(out + 2 * (size_t)n))[t] = th.v;   // elements 2n+4t..2n+4t+3
    } else if (i0 < n) {
        for (long i = i0; i < n; ++i) {
            const size_t k = (size_t)i * 3;
            float rp0, rp1, thr;
            pid_one(&ref_ve[k], &meas_ve[k], &pid_int[k], &pid_prev_err[k], &pid_prev_d[k],
                    meas_yaw[i], mass[i], rp0, rp1, thr);
            out[(size_t)i*2 + 0] = rp0;
            out[(size_t)i*2 + 1] = rp1;
            out[2*(size_t)n + i] = thr;
        }
    }
}

extern "C" void kernel_launch(void* const* d_in, const int* in_sizes, int n_in,
                              void* d_out, int out_size, void* d_ws, size_t ws_size,
                              hipStream_t stream) {
    const float* ref_ve       = (const float*)d_in[0];
    const float* meas_ve      = (const float*)d_in[1];
    const float* meas_yaw     = (const float*)d_in[2];
    const float* mass         = (const float*)d_in[3];
    const float* pid_int      = (const float*)d_in[4];
    const float* pid_prev_err = (const float*)d_in[5];
    const float* pid_prev_d   = (const float*)d_in[6];
    float* out = (float*)d_out;
    const int n = in_sizes[2];  // meas_yaw element count == N

    const int threads = (n + 3) / 4;
    const int block = 256;
    const int grid = (threads + block - 1) / block;
    pos_ctrl_kernel<<<grid, block, 0, stream>>>(
        ref_ve, meas_ve, meas_yaw, mass, pid_int, pid_prev_err, pid_prev_d, out, n);
}

// Round 4
// 270.491 us; speedup vs baseline: 1.0228x; 1.0228x over previous
//
#include <hip/hip_runtime.h>

#define G_CONST     9.81f
#define DT_VEL_     0.01f
#define MAX_THRUST_ 39.96f                 // 0.9 * 44.4
#define MAX_ANGLE_  0.5235987755982988f    // 30 deg in rad
#define ALPHA_      0.16666667f            // DT/(TAU+DT) in f32
#define TILE        256

__device__ __forceinline__ void pid_one(
    const float* rv, const float* mv, const float* pi,
    const float* pe, const float* pd,
    float yaw, float m,
    float& rp0o, float& rp1o, float& th)
{
    const float KP[3] = {2.0f, 2.0f, 4.0f};
    const float KI[3] = {0.5f, 0.5f, 1.0f};
    const float KD[3] = {0.1f, 0.1f, 0.05f};
    float u[3];
#pragma unroll
    for (int c = 0; c < 3; ++c) {
        float err   = rv[c] - mv[c];
        float integ = pi[c] + err * DT_VEL_;
        float d_raw = (err - pe[c]) / DT_VEL_;
        float d     = pd[c] + ALPHA_ * (d_raw - pd[c]);
        float uu    = KP[c] * err + KI[c] * integ + KD[c] * d;
        u[c] = fminf(fmaxf(uu, -6.0f), 6.0f);
    }
    float s, c;
    __sincosf(yaw, &s, &c);
    float rp0 = (s * u[0] - c * u[1]) / G_CONST;
    float rp1 = (c * u[0] + s * u[1]) / G_CONST;
    float mag = sqrtf(rp0 * rp0 + rp1 * rp1);
    float sc  = fminf(MAX_ANGLE_ / (mag + 1e-6f), 1.0f);
    sc = (mag > MAX_ANGLE_) ? sc : 1.0f;
    rp0o = rp0 * sc;
    rp1o = rp1 * sc;
    th = fminf(fmaxf(m * G_CONST + m * u[2], 0.8f * G_CONST * m), MAX_THRUST_);
}

__global__ __launch_bounds__(256) void pos_ctrl_lds(
    const float* __restrict__ ref_ve,
    const float* __restrict__ meas_ve,
    const float* __restrict__ meas_yaw,
    const float* __restrict__ mass,
    const float* __restrict__ pid_int,
    const float* __restrict__ pid_prev_err,
    const float* __restrict__ pid_prev_d,
    float* __restrict__ out,   // fp32: [n*2 rp interleaved][n thrust]
    int n)
{
    // 5 x 3 KB = 15 KB LDS -> 8 blocks/CU (wave-capped), 100% occupancy
    __shared__ float s_rv[TILE * 3];
    __shared__ float s_mv[TILE * 3];
    __shared__ float s_pi[TILE * 3];
    __shared__ float s_pe[TILE * 3];
    __shared__ float s_pd[TILE * 3];

    const int  tid = threadIdx.x;
    const long d0  = (long)blockIdx.x * TILE;

    if (d0 + TILE <= n) {
        // scalar per-drone inputs: stride-4 coalesced
        const float yw = meas_yaw[d0 + tid];
        const float m  = mass[d0 + tid];

        // Stage 5 vec3 arrays: 192 float4 per array, lane-contiguous (1024 B/instr)
        if (tid < (3 * TILE) / 4) {   // 192 threads
            const size_t g = (size_t)d0 * 3;  // float offset of tile; 3072B-aligned
            float4 v0 = ((const float4*)(ref_ve       + g))[tid];
            float4 v1 = ((const float4*)(meas_ve     + g))[tid];
            float4 v2 = ((const float4*)(pid_int     + g))[tid];
            float4 v3 = ((const float4*)(pid_prev_err + g))[tid];
            float4 v4 = ((const float4*)(pid_prev_d  + g))[tid];
            ((float4*)s_rv)[tid] = v0;
            ((float4*)s_mv)[tid] = v1;
            ((float4*)s_pi)[tid] = v2;
            ((float4*)s_pe)[tid] = v3;
            ((float4*)s_pd)[tid] = v4;
        }
        __syncthreads();

        const int k = tid * 3;  // LDS read at 12B stride: <=2-way bank alias (free)
        float rp0, rp1, thr;
        pid_one(&s_rv[k], &s_mv[k], &s_pi[k], &s_pe[k], &s_pd[k],
                yw, m, rp0, rp1, thr);

        ((float2*)out)[d0 + tid] = make_float2(rp0, rp1);  // stride-8, contiguous
        out[2 * (size_t)n + d0 + tid] = thr;               // stride-4, contiguous
    } else if (d0 + tid < n) {
        // tail tile (block-uniform branch; no __syncthreads on this path)
        const long i = d0 + tid;
        const size_t k = (size_t)i * 3;
        float rp0, rp1, thr;
        pid_one(&ref_ve[k], &meas_ve[k], &pid_int[k], &pid_prev_err[k], &pid_prev_d[k],
                meas_yaw[i], mass[i], rp0, rp1, thr);
        out[(size_t)i * 2 + 0] = rp0;
        out[(size_t)i * 2 + 1] = rp1;
        out[2 * (size_t)n + i] = thr;
    }
}

extern "C" void kernel_launch(void* const* d_in, const int* in_sizes, int n_in,
                              void* d_out, int out_size, void* d_ws, size_t ws_size,
                              hipStream_t stream) {
    const float* ref_ve       = (const float*)d_in[0];
    const float* meas_ve      = (const float*)d_in[1];
    const float* meas_yaw     = (const float*)d_in[2];
    const float* mass         = (const float*)d_in[3];
    const float* pid_int      = (const float*)d_in[4];
    const float* pid_prev_err = (const float*)d_in[5];
    const float* pid_prev_d   = (const float*)d_in[6];
    float* out = (float*)d_out;
    const int n = in_sizes[2];  // meas_yaw element count == N

    const int grid = (n + TILE - 1) / TILE;
    pos_ctrl_lds<<<grid, TILE, 0, stream>>>(
        ref_ve, meas_ve, meas_yaw, mass, pid_int, pid_prev_err, pid_prev_d, out, n);
}